// Round 1
// baseline (101.074 us; speedup 1.0000x reference)
//
#include <hip/hip_runtime.h>

#define LQ 2304   // sequence length = 48*48
#define CIN 192
#define EMB 256
#define NH 8
#define HD 32

typedef __attribute__((ext_vector_type(8))) short short8;
typedef __attribute__((ext_vector_type(4))) short short4v;
typedef __attribute__((ext_vector_type(4))) float floatx4;

__device__ __forceinline__ unsigned short f2bf(float f) {
  union { float f; unsigned u; } v; v.f = f;
  unsigned r = v.u + 0x7FFFu + ((v.u >> 16) & 1u);
  return (unsigned short)(r >> 16);
}
__device__ __forceinline__ unsigned pack2(float a, float b) {
  return (unsigned)f2bf(a) | ((unsigned)f2bf(b) << 16);
}

// ---------------- kernel 1: convert weights fp32 -> bf16 ----------------
__global__ void k_prep_w(const float* Wq, const float* Wk, const float* Wv,
                         unsigned short* Wqb, unsigned short* Wkb, unsigned short* Wvb) {
  const int n = EMB * CIN;
  for (int i = blockIdx.x * blockDim.x + threadIdx.x; i < n; i += gridDim.x * blockDim.x) {
    Wqb[i] = f2bf(Wq[i]);
    Wkb[i] = f2bf(Wk[i]);
    Wvb[i] = f2bf(Wv[i]);
  }
}

// ------- kernel 2: transpose (B,C,L) f32 -> (B,L,C) bf16 for query/key -------
__global__ void k_transpose(const float* q, const float* k,
                            unsigned short* Xtq, unsigned short* Xtk) {
  __shared__ float tile[64][65];
  const float* src = blockIdx.z ? k : q;
  unsigned short* dst = blockIdx.z ? Xtk : Xtq;
  int b = blockIdx.y;
  int lt = blockIdx.x % 36, ct = blockIdx.x / 36;
  int l0 = lt * 64, c0 = ct * 64;
  int j = threadIdx.x & 63, i0 = threadIdx.x >> 6;
  const float* s = src + (size_t)b * CIN * LQ;
  for (int i = i0; i < 64; i += 4)
    tile[i][j] = s[(size_t)(c0 + i) * LQ + l0 + j];
  __syncthreads();
  unsigned short* d = dst + (size_t)b * LQ * CIN;
  for (int li = i0; li < 64; li += 4)
    d[(size_t)(l0 + li) * CIN + c0 + j] = f2bf(tile[j][li]);
}

// ------- kernel 3: projection GEMM (MFMA): D^T[e][l] = sum_c W[e][c]*Xt[l][c] -------
// proj 0: Q -> Qb[b][h][l][d] bf16, scaled by log2(e)/sqrt(hd)
// proj 1: K -> Kb[b][h][l][d] bf16
// proj 2: V -> Vt[b][h][d][l] bf16 (transposed)
__global__ __launch_bounds__(256) void k_proj(
    const unsigned short* Xtq, const unsigned short* Xtk,
    const unsigned short* Wqb, const unsigned short* Wkb, const unsigned short* Wvb,
    const float* bq, const float* bk, const float* bv,
    unsigned short* Qb, unsigned short* Kb, unsigned short* Vt) {
  int proj = blockIdx.z;
  int b = blockIdx.y;
  int l0 = blockIdx.x * 16;
  const unsigned short* Xt = (proj == 0) ? Xtq : Xtk;
  const unsigned short* W  = (proj == 0) ? Wqb : (proj == 1 ? Wkb : Wvb);
  const float* bias        = (proj == 0) ? bq  : (proj == 1 ? bk  : bv);
  const float alpha = (proj == 0) ? 0.25505653582177047f : 1.0f; // log2(e)/sqrt(32)

  int lane = threadIdx.x & 63, w = threadIdx.x >> 6;
  int g = lane >> 4, r16 = lane & 15;
  int e0 = w * 64;
  int lg = l0 + r16;

  floatx4 acc[4];
  #pragma unroll
  for (int a = 0; a < 4; ++a) acc[a] = (floatx4){0.f, 0.f, 0.f, 0.f};

  const unsigned short* xrow = Xt + ((size_t)b * LQ + lg) * CIN + g * 8;
  #pragma unroll
  for (int ks = 0; ks < CIN; ks += 32) {
    short8 xf = *(const short8*)(xrow + ks);
    #pragma unroll
    for (int a = 0; a < 4; ++a) {
      short8 wf = *(const short8*)(W + (size_t)(e0 + a * 16 + r16) * CIN + ks + g * 8);
      acc[a] = __builtin_amdgcn_mfma_f32_16x16x32_bf16(wf, xf, acc[a], 0, 0, 0);
    }
  }

  #pragma unroll
  for (int a = 0; a < 4; ++a) {
    int ebase = e0 + a * 16 + g * 4;       // 4 consecutive e rows (4-aligned, same head)
    int h = ebase >> 5, d0 = ebase & 31;
    if (proj < 2) {
      unsigned short* outp = (proj == 0) ? Qb : Kb;
      short4v pk;
      #pragma unroll
      for (int r = 0; r < 4; ++r)
        pk[r] = (short)f2bf((acc[a][r] + bias[ebase + r]) * alpha);
      *(short4v*)(outp + ((size_t)(b * NH + h) * LQ + lg) * HD + d0) = pk;
    } else {
      #pragma unroll
      for (int r = 0; r < 4; ++r)
        Vt[((size_t)(b * NH + h) * HD + d0 + r) * LQ + lg] =
            f2bf(acc[a][r] + bias[ebase + r]);
    }
  }
}

// ---------------- kernel 4: causal flash attention ----------------
// S^T = mfma(K_rows, Q_cols): lane owns q = q0+(lane&15); k = kb + half*16 + g*4 + r
// O^T = mfma(Vt_rows, P^T):   lane owns d-rows, q col; output already (B,E,L)
__global__ __launch_bounds__(256) void k_attn(const unsigned short* Qb,
                                              const unsigned short* Kb,
                                              const unsigned short* Vt,
                                              float* out) {
  int bh = blockIdx.y;
  int w = threadIdx.x >> 6, lane = threadIdx.x & 63;
  int g = lane >> 4, qq = lane & 15;
  int qblk = 35 - blockIdx.x;               // heavy (large-q0) blocks first
  int q0 = qblk * 64 + w * 16;
  int qg = q0 + qq;

  short8 qf = *(const short8*)(Qb + ((size_t)bh * LQ + qg) * HD + g * 8);

  const floatx4 z = (floatx4){0.f, 0.f, 0.f, 0.f};
  floatx4 o0 = z, o1 = z;
  float m = -1e30f, sum = 0.f;

  const unsigned short* Kbase = Kb + (size_t)bh * LQ * HD;
  const unsigned short* Vbase = Vt + (size_t)bh * HD * LQ;
  int ntiles = ((q0 + 15) >> 5) + 1;

  for (int t = 0; t < ntiles; ++t) {
    int kb = t * 32;
    short8 kf0 = *(const short8*)(Kbase + (size_t)(kb + qq) * HD + g * 8);
    short8 kf1 = *(const short8*)(Kbase + (size_t)(kb + 16 + qq) * HD + g * 8);
    short8 vf0 = *(const short8*)(Vbase + (size_t)qq * LQ + kb + g * 8);
    short8 vf1 = *(const short8*)(Vbase + (size_t)(16 + qq) * LQ + kb + g * 8);

    floatx4 c0 = __builtin_amdgcn_mfma_f32_16x16x32_bf16(kf0, qf, z, 0, 0, 0);
    floatx4 c1 = __builtin_amdgcn_mfma_f32_16x16x32_bf16(kf1, qf, z, 0, 0, 0);

    float s[8];
    #pragma unroll
    for (int r = 0; r < 4; ++r) { s[r] = c0[r]; s[4 + r] = c1[r]; }
    if (kb + 31 > q0) {                      // diagonal tiles: causal mask
      #pragma unroll
      for (int r = 0; r < 4; ++r) {
        if (kb + g * 4 + r > qg)      s[r]     = -1e30f;
        if (kb + 16 + g * 4 + r > qg) s[4 + r] = -1e30f;
      }
    }

    float mt = s[0];
    #pragma unroll
    for (int i = 1; i < 8; ++i) mt = fmaxf(mt, s[i]);
    mt = fmaxf(mt, __shfl_xor(mt, 16));
    mt = fmaxf(mt, __shfl_xor(mt, 32));
    float mn = fmaxf(m, mt);
    float alpha = exp2f(m - mn);
    float p[8], ts = 0.f;
    #pragma unroll
    for (int i = 0; i < 8; ++i) { p[i] = exp2f(s[i] - mn); ts += p[i]; }
    ts += __shfl_xor(ts, 16);
    ts += __shfl_xor(ts, 32);
    sum = sum * alpha + ts;
    m = mn;
    #pragma unroll
    for (int r = 0; r < 4; ++r) { o0[r] *= alpha; o1[r] *= alpha; }

    // redistribute P (C-layout) -> P^T B-fragment via 8 lane shuffles
    unsigned pr01 = pack2(p[0], p[1]), pr23 = pack2(p[2], p[3]);
    unsigned pr45 = pack2(p[4], p[5]), pr67 = pack2(p[6], p[7]);
    int src1 = (((2 * g) & 3) << 4) | qq;
    int src2 = src1 + 16;
    int x0 = __shfl((int)pr01, src1), x1 = __shfl((int)pr23, src1);
    int x2 = __shfl((int)pr01, src2), x3 = __shfl((int)pr23, src2);
    int y0 = __shfl((int)pr45, src1), y1 = __shfl((int)pr67, src1);
    int y2 = __shfl((int)pr45, src2), y3 = __shfl((int)pr67, src2);
    union { int i[4]; short8 s8; } pf;
    pf.i[0] = (g < 2) ? x0 : y0;
    pf.i[1] = (g < 2) ? x1 : y1;
    pf.i[2] = (g < 2) ? x2 : y2;
    pf.i[3] = (g < 2) ? x3 : y3;

    o0 = __builtin_amdgcn_mfma_f32_16x16x32_bf16(vf0, pf.s8, o0, 0, 0, 0);
    o1 = __builtin_amdgcn_mfma_f32_16x16x32_bf16(vf1, pf.s8, o1, 0, 0, 0);
  }

  float inv = 1.0f / sum;
  #pragma unroll
  for (int r = 0; r < 4; ++r) {
    out[((size_t)bh * HD + g * 4 + r) * LQ + qg]      = o0[r] * inv;
    out[((size_t)bh * HD + 16 + g * 4 + r) * LQ + qg] = o1[r] * inv;
  }
}

extern "C" void kernel_launch(void* const* d_in, const int* in_sizes, int n_in,
                              void* d_out, int out_size, void* d_ws, size_t ws_size,
                              hipStream_t stream) {
  const float* query = (const float*)d_in[0];
  const float* key   = (const float*)d_in[1];
  const float* Wq    = (const float*)d_in[2];
  const float* bq    = (const float*)d_in[3];
  const float* Wk    = (const float*)d_in[4];
  const float* bk    = (const float*)d_in[5];
  const float* Wv    = (const float*)d_in[6];
  const float* bv    = (const float*)d_in[7];
  float* out = (float*)d_out;

  unsigned short* Wqb = (unsigned short*)d_ws;
  unsigned short* Wkb = Wqb + EMB * CIN;
  unsigned short* Wvb = Wkb + EMB * CIN;
  unsigned short* Xtq = Wvb + EMB * CIN;
  unsigned short* Xtk = Xtq + 2 * LQ * CIN;
  unsigned short* Qb  = Xtk + 2 * LQ * CIN;
  unsigned short* Kb  = Qb + 2 * NH * LQ * HD;
  unsigned short* Vt  = Kb + 2 * NH * LQ * HD;

  hipLaunchKernelGGL(k_prep_w, dim3(64), dim3(256), 0, stream,
                     Wq, Wk, Wv, Wqb, Wkb, Wvb);
  hipLaunchKernelGGL(k_transpose, dim3(108, 2, 2), dim3(256), 0, stream,
                     query, key, Xtq, Xtk);
  hipLaunchKernelGGL(k_proj, dim3(144, 2, 3), dim3(256), 0, stream,
                     Xtq, Xtk, Wqb, Wkb, Wvb, bq, bk, bv, Qb, Kb, Vt);
  hipLaunchKernelGGL(k_attn, dim3(36, 16), dim3(256), 0, stream,
                     Qb, Kb, Vt, out);
}

// Round 2
// 73.234 us; speedup vs baseline: 1.3801x; 1.3801x over previous
//
#include <hip/hip_runtime.h>

#define LQ 2304   // sequence length = 48*48
#define CIN 192
#define EMB 256
#define NH 8
#define HD 32

typedef __attribute__((ext_vector_type(8))) short short8;
typedef __attribute__((ext_vector_type(4))) short short4v;
typedef __attribute__((ext_vector_type(4))) float floatx4;

__device__ __forceinline__ unsigned short f2bf(float f) {
  union { float f; unsigned u; } v; v.f = f;
  unsigned r = v.u + 0x7FFFu + ((v.u >> 16) & 1u);
  return (unsigned short)(r >> 16);
}
__device__ __forceinline__ unsigned cvtpk(float lo, float hi) {
  unsigned r;
  asm("v_cvt_pk_bf16_f32 %0, %1, %2" : "=v"(r) : "v"(lo), "v"(hi));
  return r;
}

// ---------------- kernel 1: convert weights fp32 -> bf16 ----------------
__global__ void k_prep_w(const float* __restrict__ Wq, const float* __restrict__ Wk,
                         const float* __restrict__ Wv,
                         unsigned short* Wqb, unsigned short* Wkb, unsigned short* Wvb) {
  const int n = EMB * CIN;
  for (int i = blockIdx.x * blockDim.x + threadIdx.x; i < n; i += gridDim.x * blockDim.x) {
    Wqb[i] = f2bf(Wq[i]);
    Wkb[i] = f2bf(Wk[i]);
    Wvb[i] = f2bf(Wv[i]);
  }
}

// ------- kernel 2: transpose (B,C,L) f32 -> (B,L,C) bf16 for query/key -------
__global__ void k_transpose(const float* __restrict__ q, const float* __restrict__ k,
                            unsigned short* Xtq, unsigned short* Xtk) {
  __shared__ float tile[64][65];
  const float* src = blockIdx.z ? k : q;
  unsigned short* dst = blockIdx.z ? Xtk : Xtq;
  int b = blockIdx.y;
  int lt = blockIdx.x % 36, ct = blockIdx.x / 36;
  int l0 = lt * 64, c0 = ct * 64;
  int j = threadIdx.x & 63, i0 = threadIdx.x >> 6;
  const float* s = src + (size_t)b * CIN * LQ;
  for (int i = i0; i < 64; i += 4)
    tile[i][j] = s[(size_t)(c0 + i) * LQ + l0 + j];
  __syncthreads();
  unsigned short* d = dst + (size_t)b * LQ * CIN;
  for (int li = i0; li < 64; li += 4)
    d[(size_t)(l0 + li) * CIN + c0 + j] = f2bf(tile[j][li]);
}

// ------- kernel 3: projection GEMM (MFMA): D^T[e][l] = sum_c W[e][c]*Xt[l][c] -------
__global__ __launch_bounds__(256) void k_proj(
    const unsigned short* __restrict__ Xtq, const unsigned short* __restrict__ Xtk,
    const unsigned short* __restrict__ Wqb, const unsigned short* __restrict__ Wkb,
    const unsigned short* __restrict__ Wvb,
    const float* __restrict__ bq, const float* __restrict__ bk, const float* __restrict__ bv,
    unsigned short* Qb, unsigned short* Kb, unsigned short* Vt) {
  int proj = blockIdx.z;
  int b = blockIdx.y;
  int l0 = blockIdx.x * 16;
  const unsigned short* Xt = (proj == 0) ? Xtq : Xtk;
  const unsigned short* W  = (proj == 0) ? Wqb : (proj == 1 ? Wkb : Wvb);
  const float* bias        = (proj == 0) ? bq  : (proj == 1 ? bk  : bv);
  const float alpha = (proj == 0) ? 0.25505653582177047f : 1.0f; // log2(e)/sqrt(32)

  int lane = threadIdx.x & 63, w = threadIdx.x >> 6;
  int g = lane >> 4, r16 = lane & 15;
  int e0 = w * 64;
  int lg = l0 + r16;

  floatx4 acc[4];
  #pragma unroll
  for (int a = 0; a < 4; ++a) acc[a] = (floatx4){0.f, 0.f, 0.f, 0.f};

  const unsigned short* xrow = Xt + ((size_t)b * LQ + lg) * CIN + g * 8;
  #pragma unroll
  for (int ks = 0; ks < CIN; ks += 32) {
    short8 xf = *(const short8*)(xrow + ks);
    #pragma unroll
    for (int a = 0; a < 4; ++a) {
      short8 wf = *(const short8*)(W + (size_t)(e0 + a * 16 + r16) * CIN + ks + g * 8);
      acc[a] = __builtin_amdgcn_mfma_f32_16x16x32_bf16(wf, xf, acc[a], 0, 0, 0);
    }
  }

  #pragma unroll
  for (int a = 0; a < 4; ++a) {
    int ebase = e0 + a * 16 + g * 4;
    int h = ebase >> 5, d0 = ebase & 31;
    if (proj < 2) {
      unsigned short* outp = (proj == 0) ? Qb : Kb;
      short4v pk;
      #pragma unroll
      for (int r = 0; r < 4; ++r)
        pk[r] = (short)f2bf((acc[a][r] + bias[ebase + r]) * alpha);
      *(short4v*)(outp + ((size_t)(b * NH + h) * LQ + lg) * HD + d0) = pk;
    } else {
      #pragma unroll
      for (int r = 0; r < 4; ++r)
        Vt[((size_t)(b * NH + h) * HD + d0 + r) * LQ + lg] =
            f2bf(acc[a][r] + bias[ebase + r]);
    }
  }
}

// ---------------- kernel 4: causal flash attention, k-striped ----------------
// Block = 16 q rows; 4 waves stripe 64-wide k super-tiles; LDS combine.
__device__ __forceinline__ short8 redist(unsigned p01, unsigned p23, unsigned p45,
                                         unsigned p67, int src1, int src2, int g) {
  int x0 = __shfl((int)p01, src1), x1 = __shfl((int)p23, src1);
  int x2 = __shfl((int)p01, src2), x3 = __shfl((int)p23, src2);
  int y0 = __shfl((int)p45, src1), y1 = __shfl((int)p67, src1);
  int y2 = __shfl((int)p45, src2), y3 = __shfl((int)p67, src2);
  union { int i[4]; short8 s8; } pf;
  pf.i[0] = (g < 2) ? x0 : y0;
  pf.i[1] = (g < 2) ? x1 : y1;
  pf.i[2] = (g < 2) ? x2 : y2;
  pf.i[3] = (g < 2) ? x3 : y3;
  return pf.s8;
}

__global__ __launch_bounds__(256, 4) void k_attn(const unsigned short* __restrict__ Qb,
                                                 const unsigned short* __restrict__ Kb,
                                                 const unsigned short* __restrict__ Vt,
                                                 float* __restrict__ out) {
  __shared__ float Osh[4][32][17];
  __shared__ float Msh[4][16];
  __shared__ float Ssh[4][16];

  // XCD-grouped, heavy-first mapping: same head's blocks land on one XCD's L2
  int bid = blockIdx.x;               // 0..2303
  int xcd = bid & 7;
  int idx = bid >> 3;                 // 0..287
  int half = idx / 144;
  int bh = xcd + 8 * half;            // 0..15
  int j = 143 - (idx - half * 144);   // q-tile index, heavy first

  int w = threadIdx.x >> 6, lane = threadIdx.x & 63;
  int g = lane >> 4, qq = lane & 15;
  int q0b = j * 16;
  int qg = q0b + qq;

  short8 qf = *(const short8*)(Qb + ((size_t)bh * LQ + qg) * HD + g * 8);

  const floatx4 z = (floatx4){0.f, 0.f, 0.f, 0.f};
  floatx4 o0 = z, o1 = z;
  float m = -1e30f, sum = 0.f;

  const unsigned short* Kbase = Kb + (size_t)bh * LQ * HD;
  const unsigned short* Vbase = Vt + (size_t)bh * HD * LQ;
  int ntiles = (16 * j + 16 + 63) >> 6;   // 64-wide super-tiles
  int src1 = (((2 * g) & 3) << 4) | qq;
  int src2 = src1 + 16;

  int t = w;
  short8 kf[4];
  if (t < ntiles) {
    int k0 = t * 64;
    #pragma unroll
    for (int i = 0; i < 4; ++i)
      kf[i] = *(const short8*)(Kbase + (size_t)(k0 + i * 16 + qq) * HD + g * 8);
  }

  while (t < ntiles) {
    int k0 = t * 64;
    int tn = t + 4;
    int kpre = ((tn < ntiles) ? tn : t) * 64;

    // prefetch next K tile (overlaps with softmax+PV below)
    short8 kn[4];
    #pragma unroll
    for (int i = 0; i < 4; ++i)
      kn[i] = *(const short8*)(Kbase + (size_t)(kpre + i * 16 + qq) * HD + g * 8);

    // V fragments for this tile (issued early; consumed after softmax)
    short8 vf0 = *(const short8*)(Vbase + (size_t)qq * LQ + k0 + g * 8);
    short8 vf1 = *(const short8*)(Vbase + (size_t)(16 + qq) * LQ + k0 + g * 8);
    short8 vf2 = *(const short8*)(Vbase + (size_t)qq * LQ + k0 + 32 + g * 8);
    short8 vf3 = *(const short8*)(Vbase + (size_t)(16 + qq) * LQ + k0 + 32 + g * 8);

    floatx4 c0 = __builtin_amdgcn_mfma_f32_16x16x32_bf16(kf[0], qf, z, 0, 0, 0);
    floatx4 c1 = __builtin_amdgcn_mfma_f32_16x16x32_bf16(kf[1], qf, z, 0, 0, 0);
    floatx4 c2 = __builtin_amdgcn_mfma_f32_16x16x32_bf16(kf[2], qf, z, 0, 0, 0);
    floatx4 c3 = __builtin_amdgcn_mfma_f32_16x16x32_bf16(kf[3], qf, z, 0, 0, 0);

    float s[16];
    #pragma unroll
    for (int r = 0; r < 4; ++r) {
      s[r] = c0[r]; s[4 + r] = c1[r]; s[8 + r] = c2[r]; s[12 + r] = c3[r];
    }
    if (t == ntiles - 1) {              // only the diagonal tile needs masking
      #pragma unroll
      for (int i = 0; i < 4; ++i)
        #pragma unroll
        for (int r = 0; r < 4; ++r)
          if (k0 + i * 16 + g * 4 + r > qg) s[i * 4 + r] = -1e30f;
    }

    float mt = s[0];
    #pragma unroll
    for (int i = 1; i < 16; ++i) mt = fmaxf(mt, s[i]);
    mt = fmaxf(mt, __shfl_xor(mt, 16));
    mt = fmaxf(mt, __shfl_xor(mt, 32));
    float mn = fmaxf(m, mt);
    float alpha = exp2f(m - mn);
    float p[16], ts = 0.f;
    #pragma unroll
    for (int i = 0; i < 16; ++i) { p[i] = exp2f(s[i] - mn); ts += p[i]; }
    ts += __shfl_xor(ts, 16);
    ts += __shfl_xor(ts, 32);
    sum = sum * alpha + ts;
    m = mn;
    #pragma unroll
    for (int r = 0; r < 4; ++r) { o0[r] *= alpha; o1[r] *= alpha; }

    // pack + redistribute P -> B-fragments (two 32-k halves)
    short8 pfA = redist(cvtpk(p[0], p[1]), cvtpk(p[2], p[3]),
                        cvtpk(p[4], p[5]), cvtpk(p[6], p[7]), src1, src2, g);
    short8 pfB = redist(cvtpk(p[8], p[9]), cvtpk(p[10], p[11]),
                        cvtpk(p[12], p[13]), cvtpk(p[14], p[15]), src1, src2, g);

    o0 = __builtin_amdgcn_mfma_f32_16x16x32_bf16(vf0, pfA, o0, 0, 0, 0);
    o1 = __builtin_amdgcn_mfma_f32_16x16x32_bf16(vf1, pfA, o1, 0, 0, 0);
    o0 = __builtin_amdgcn_mfma_f32_16x16x32_bf16(vf2, pfB, o0, 0, 0, 0);
    o1 = __builtin_amdgcn_mfma_f32_16x16x32_bf16(vf3, pfB, o1, 0, 0, 0);

    kf[0] = kn[0]; kf[1] = kn[1]; kf[2] = kn[2]; kf[3] = kn[3];
    t = tn;
  }

  // ---- combine the 4 waves' partial (m, sum, O) ----
  #pragma unroll
  for (int r = 0; r < 4; ++r) {
    Osh[w][g * 4 + r][qq] = o0[r];
    Osh[w][16 + g * 4 + r][qq] = o1[r];
  }
  if (g == 0) { Msh[w][qq] = m; Ssh[w][qq] = sum; }
  __syncthreads();

  int tid = threadIdx.x;
  int dd = tid >> 4, q = tid & 15;
  float m0 = Msh[0][q], m1 = Msh[1][q], m2 = Msh[2][q], m3 = Msh[3][q];
  float ms = fmaxf(fmaxf(m0, m1), fmaxf(m2, m3));
  float a0 = exp2f(m0 - ms), a1 = exp2f(m1 - ms);
  float a2 = exp2f(m2 - ms), a3 = exp2f(m3 - ms);
  float ss = a0 * Ssh[0][q] + a1 * Ssh[1][q] + a2 * Ssh[2][q] + a3 * Ssh[3][q];
  float inv = 1.0f / ss;
  float olo = a0 * Osh[0][dd][q] + a1 * Osh[1][dd][q] +
              a2 * Osh[2][dd][q] + a3 * Osh[3][dd][q];
  float ohi = a0 * Osh[0][dd + 16][q] + a1 * Osh[1][dd + 16][q] +
              a2 * Osh[2][dd + 16][q] + a3 * Osh[3][dd + 16][q];
  out[((size_t)bh * HD + dd) * LQ + q0b + q] = olo * inv;
  out[((size_t)bh * HD + dd + 16) * LQ + q0b + q] = ohi * inv;
}

extern "C" void kernel_launch(void* const* d_in, const int* in_sizes, int n_in,
                              void* d_out, int out_size, void* d_ws, size_t ws_size,
                              hipStream_t stream) {
  const float* query = (const float*)d_in[0];
  const float* key   = (const float*)d_in[1];
  const float* Wq    = (const float*)d_in[2];
  const float* bq    = (const float*)d_in[3];
  const float* Wk    = (const float*)d_in[4];
  const float* bk    = (const float*)d_in[5];
  const float* Wv    = (const float*)d_in[6];
  const float* bv    = (const float*)d_in[7];
  float* out = (float*)d_out;

  unsigned short* Wqb = (unsigned short*)d_ws;
  unsigned short* Wkb = Wqb + EMB * CIN;
  unsigned short* Wvb = Wkb + EMB * CIN;
  unsigned short* Xtq = Wvb + EMB * CIN;
  unsigned short* Xtk = Xtq + 2 * LQ * CIN;
  unsigned short* Qb  = Xtk + 2 * LQ * CIN;
  unsigned short* Kb  = Qb + 2 * NH * LQ * HD;
  unsigned short* Vt  = Kb + 2 * NH * LQ * HD;

  hipLaunchKernelGGL(k_prep_w, dim3(64), dim3(256), 0, stream,
                     Wq, Wk, Wv, Wqb, Wkb, Wvb);
  hipLaunchKernelGGL(k_transpose, dim3(108, 2, 2), dim3(256), 0, stream,
                     query, key, Xtq, Xtk);
  hipLaunchKernelGGL(k_proj, dim3(144, 2, 3), dim3(256), 0, stream,
                     Xtq, Xtk, Wqb, Wkb, Wvb, bq, bk, bv, Qb, Kb, Vt);
  hipLaunchKernelGGL(k_attn, dim3(2304), dim3(256), 0, stream,
                     Qb, Kb, Vt, out);
}

// Round 3
// 51.004 us; speedup vs baseline: 1.9817x; 1.4358x over previous
//
#include <hip/hip_runtime.h>

#define LQ 2304   // sequence length = 48*48
#define CIN 192
#define EMB 256
#define NH 8
#define HD 32

typedef __attribute__((ext_vector_type(8))) short short8;
typedef __attribute__((ext_vector_type(4))) short short4v;
typedef __attribute__((ext_vector_type(4))) float floatx4;
typedef __attribute__((ext_vector_type(16))) float f32x16;

__device__ __forceinline__ unsigned short f2bf(float f) {
  union { float f; unsigned u; } v; v.f = f;
  unsigned r = v.u + 0x7FFFu + ((v.u >> 16) & 1u);
  return (unsigned short)(r >> 16);
}
__device__ __forceinline__ unsigned cvtpk(float lo, float hi) {
  unsigned r;
  asm("v_cvt_pk_bf16_f32 %0, %1, %2" : "=v"(r) : "v"(lo), "v"(hi));
  return r;
}
// exchange halves: a' = {a_lo, b_from_partner}; b' = {a_from_partner, b_hi}
__device__ __forceinline__ void plswap(unsigned& a, unsigned& b, int hi) {
#if __has_builtin(__builtin_amdgcn_permlane32_swap)
  auto r = __builtin_amdgcn_permlane32_swap((int)a, (int)b, false, false);
  a = (unsigned)r[0]; b = (unsigned)r[1];
#else
  unsigned pa = (unsigned)__shfl_xor((int)a, 32);
  unsigned pb = (unsigned)__shfl_xor((int)b, 32);
  unsigned na = hi ? pb : a;
  unsigned nb = hi ? b : pa;
  a = na; b = nb;
#endif
}
__device__ __forceinline__ float xmax(float x, int hi) {
  unsigned a = __float_as_uint(x), b = a;
  plswap(a, b, hi);
  return fmaxf(__uint_as_float(a), __uint_as_float(b));
}
__device__ __forceinline__ float xadd(float x, int hi) {
  unsigned a = __float_as_uint(x), b = a;
  plswap(a, b, hi);
  return __uint_as_float(a) + __uint_as_float(b);
}

// ------- kernel 1: fused weight-cast + input transpose -------
// z=0: transpose query; z=1: transpose key; z=2: cast W's
__global__ void k_prep(const float* __restrict__ q, const float* __restrict__ k,
                       const float* __restrict__ Wq, const float* __restrict__ Wk,
                       const float* __restrict__ Wv,
                       unsigned short* Xtq, unsigned short* Xtk,
                       unsigned short* Wqb, unsigned short* Wkb, unsigned short* Wvb) {
  if (blockIdx.z == 2) {
    const int n = EMB * CIN;
    int i = (blockIdx.x + 108 * blockIdx.y) * 256 + threadIdx.x;
    if (i < n) { Wqb[i] = f2bf(Wq[i]); Wkb[i] = f2bf(Wk[i]); Wvb[i] = f2bf(Wv[i]); }
    return;
  }
  __shared__ float tile[64][65];
  const float* src = blockIdx.z ? k : q;
  unsigned short* dst = blockIdx.z ? Xtk : Xtq;
  int b = blockIdx.y;
  int lt = blockIdx.x % 36, ct = blockIdx.x / 36;
  int l0 = lt * 64, c0 = ct * 64;
  int j = threadIdx.x & 63, i0 = threadIdx.x >> 6;
  const float* s = src + (size_t)b * CIN * LQ;
  for (int i = i0; i < 64; i += 4)
    tile[i][j] = s[(size_t)(c0 + i) * LQ + l0 + j];
  __syncthreads();
  unsigned short* d = dst + (size_t)b * LQ * CIN;
  for (int li = i0; li < 64; li += 4)
    d[(size_t)(l0 + li) * CIN + c0 + j] = f2bf(tile[j][li]);
}

// ------- kernel 2: projection GEMM (MFMA) -------
__global__ __launch_bounds__(256) void k_proj(
    const unsigned short* __restrict__ Xtq, const unsigned short* __restrict__ Xtk,
    const unsigned short* __restrict__ Wqb, const unsigned short* __restrict__ Wkb,
    const unsigned short* __restrict__ Wvb,
    const float* __restrict__ bq, const float* __restrict__ bk, const float* __restrict__ bv,
    unsigned short* Qb, unsigned short* Kb, unsigned short* Vt) {
  int proj = blockIdx.z;
  int b = blockIdx.y;
  int l0 = blockIdx.x * 16;
  const unsigned short* Xt = (proj == 0) ? Xtq : Xtk;
  const unsigned short* W  = (proj == 0) ? Wqb : (proj == 1 ? Wkb : Wvb);
  const float* bias        = (proj == 0) ? bq  : (proj == 1 ? bk  : bv);
  const float alpha = (proj == 0) ? 0.25505653582177047f : 1.0f; // log2(e)/sqrt(32)

  int lane = threadIdx.x & 63, w = threadIdx.x >> 6;
  int g = lane >> 4, r16 = lane & 15;
  int e0 = w * 64;
  int lg = l0 + r16;

  floatx4 acc[4];
  #pragma unroll
  for (int a = 0; a < 4; ++a) acc[a] = (floatx4){0.f, 0.f, 0.f, 0.f};

  const unsigned short* xrow = Xt + ((size_t)b * LQ + lg) * CIN + g * 8;
  #pragma unroll
  for (int ks = 0; ks < CIN; ks += 32) {
    short8 xf = *(const short8*)(xrow + ks);
    #pragma unroll
    for (int a = 0; a < 4; ++a) {
      short8 wf = *(const short8*)(W + (size_t)(e0 + a * 16 + r16) * CIN + ks + g * 8);
      acc[a] = __builtin_amdgcn_mfma_f32_16x16x32_bf16(wf, xf, acc[a], 0, 0, 0);
    }
  }

  #pragma unroll
  for (int a = 0; a < 4; ++a) {
    int ebase = e0 + a * 16 + g * 4;
    int h = ebase >> 5, d0 = ebase & 31;
    if (proj < 2) {
      unsigned short* outp = (proj == 0) ? Qb : Kb;
      short4v pk;
      #pragma unroll
      for (int r = 0; r < 4; ++r)
        pk[r] = (short)f2bf((acc[a][r] + bias[ebase + r]) * alpha);
      *(short4v*)(outp + ((size_t)(b * NH + h) * LQ + lg) * HD + d0) = pk;
    } else {
      #pragma unroll
      for (int r = 0; r < 4; ++r)
        Vt[((size_t)(b * NH + h) * HD + d0 + r) * LQ + lg] =
            f2bf(acc[a][r] + bias[ebase + r]);
    }
  }
}

// ------- kernel 3: causal flash attention, 32x32 MFMA, in-register softmax -------
// Block = 32 q rows; 4 waves stripe 64-wide k tiles; LDS combine at end.
__global__ __launch_bounds__(256, 3) void k_attn(const unsigned short* __restrict__ Qb,
                                                 const unsigned short* __restrict__ Kb,
                                                 const unsigned short* __restrict__ Vt,
                                                 float* __restrict__ out) {
  __shared__ float Osh[4][32][33];
  __shared__ float Msh[4][32];
  __shared__ float Ssh[4][32];

  int bid = blockIdx.x;               // 0..1151
  int xcd = bid & 7;
  int idx = bid >> 3;                 // 0..143
  int half = idx / 72;
  int j = 71 - (idx - half * 72);     // heavy q-tiles first
  int bh = xcd + 8 * half;
  int q0b = j * 32;

  int w = threadIdx.x >> 6, lane = threadIdx.x & 63;
  int qcol = lane & 31, hi = lane >> 5;
  int qg = q0b + qcol;

  const unsigned short* Qrow = Qb + ((size_t)bh * LQ + qg) * HD + hi * 8;
  short8 qf0 = *(const short8*)(Qrow);
  short8 qf1 = *(const short8*)(Qrow + 16);

  const f32x16 Z16 = {0,0,0,0,0,0,0,0,0,0,0,0,0,0,0,0};
  f32x16 O = Z16;
  float m = -1e30f, sum = 0.f;

  const unsigned short* Kbase = Kb + (size_t)bh * LQ * HD;
  const unsigned short* Vbase = Vt + (size_t)bh * HD * LQ;
  int ntiles = (q0b + 95) >> 6;       // ceil((q0b+32)/64)

  int t = w;
  short8 kf[4];
  if (t < ntiles) {
    const unsigned short* kr = Kbase + (size_t)(t * 64 + qcol) * HD + hi * 8;
    kf[0] = *(const short8*)(kr);
    kf[1] = *(const short8*)(kr + 16);
    kf[2] = *(const short8*)(kr + 32 * HD);
    kf[3] = *(const short8*)(kr + 32 * HD + 16);
  }

  while (t < ntiles) {
    int k0 = t * 64;
    int tn = t + 4;
    int kpre = ((tn < ntiles) ? tn : t) * 64;

    // prefetch next K stripe (hidden under softmax+PV)
    short8 kn[4];
    {
      const unsigned short* kr = Kbase + (size_t)(kpre + qcol) * HD + hi * 8;
      kn[0] = *(const short8*)(kr);
      kn[1] = *(const short8*)(kr + 16);
      kn[2] = *(const short8*)(kr + 32 * HD);
      kn[3] = *(const short8*)(kr + 32 * HD + 16);
    }
    // V fragments for this tile
    short8 vf[4];
    {
      const unsigned short* vr = Vbase + (size_t)qcol * LQ + k0 + hi * 8;
      vf[0] = *(const short8*)(vr);
      vf[1] = *(const short8*)(vr + 16);
      vf[2] = *(const short8*)(vr + 32);
      vf[3] = *(const short8*)(vr + 48);
    }

    __builtin_amdgcn_s_setprio(1);
    f32x16 c0 = __builtin_amdgcn_mfma_f32_32x32x16_bf16(kf[0], qf0, Z16, 0, 0, 0);
    c0 = __builtin_amdgcn_mfma_f32_32x32x16_bf16(kf[1], qf1, c0, 0, 0, 0);
    f32x16 c1 = __builtin_amdgcn_mfma_f32_32x32x16_bf16(kf[2], qf0, Z16, 0, 0, 0);
    c1 = __builtin_amdgcn_mfma_f32_32x32x16_bf16(kf[3], qf1, c1, 0, 0, 0);
    __builtin_amdgcn_s_setprio(0);

    if (t == ntiles - 1) {            // diagonal tile: causal mask
      #pragma unroll
      for (int i = 0; i < 16; ++i) {
        int kg = k0 + (i & 3) + 8 * (i >> 2) + 4 * hi;
        if (kg > qg)      c0[i] = -1e30f;
        if (kg + 32 > qg) c1[i] = -1e30f;
      }
    }

    // tile max: 31-op tree + one half-exchange (all VALU)
    float mx;
    {
      float a0 = fmaxf(fmaxf(c0[0], c0[8]),  fmaxf(c1[0], c1[8]));
      float a1 = fmaxf(fmaxf(c0[1], c0[9]),  fmaxf(c1[1], c1[9]));
      float a2 = fmaxf(fmaxf(c0[2], c0[10]), fmaxf(c1[2], c1[10]));
      float a3 = fmaxf(fmaxf(c0[3], c0[11]), fmaxf(c1[3], c1[11]));
      float a4 = fmaxf(fmaxf(c0[4], c0[12]), fmaxf(c1[4], c1[12]));
      float a5 = fmaxf(fmaxf(c0[5], c0[13]), fmaxf(c1[5], c1[13]));
      float a6 = fmaxf(fmaxf(c0[6], c0[14]), fmaxf(c1[6], c1[14]));
      float a7 = fmaxf(fmaxf(c0[7], c0[15]), fmaxf(c1[7], c1[15]));
      mx = fmaxf(fmaxf(fmaxf(a0, a1), fmaxf(a2, a3)),
                 fmaxf(fmaxf(a4, a5), fmaxf(a6, a7)));
    }
    mx = xmax(mx, hi);

    // deferred-max: rescale only when the running max grows by > 8
    if (!__all(mx - m <= 8.0f)) {
      float mn = fmaxf(m, mx);
      float al = exp2f(m - mn);
      sum *= al;
      #pragma unroll
      for (int i = 0; i < 16; ++i) O[i] *= al;
      m = mn;
    }

    #pragma unroll
    for (int i = 0; i < 16; ++i) {
      c0[i] = exp2f(c0[i] - m);
      c1[i] = exp2f(c1[i] - m);
    }
    // tile sum: tree + half-exchange
    {
      float a0 = (c0[0] + c0[8])  + (c1[0] + c1[8]);
      float a1 = (c0[1] + c0[9])  + (c1[1] + c1[9]);
      float a2 = (c0[2] + c0[10]) + (c1[2] + c1[10]);
      float a3 = (c0[3] + c0[11]) + (c1[3] + c1[11]);
      float a4 = (c0[4] + c0[12]) + (c1[4] + c1[12]);
      float a5 = (c0[5] + c0[13]) + (c1[5] + c1[13]);
      float a6 = (c0[6] + c0[14]) + (c1[6] + c1[14]);
      float a7 = (c0[7] + c0[15]) + (c1[7] + c1[15]);
      float ts = ((a0 + a1) + (a2 + a3)) + ((a4 + a5) + (a6 + a7));
      sum += xadd(ts, hi);
    }

    // P -> bf16 B-fragments: 16 cvt_pk + 8 permlane swaps, then PV
    union { unsigned u[4]; short8 s; } pA, pB, pC, pD;
    {
      unsigned a = cvtpk(c0[0], c0[1]), b = cvtpk(c0[2], c0[3]);
      unsigned c = cvtpk(c0[4], c0[5]), d = cvtpk(c0[6], c0[7]);
      plswap(a, c, hi); plswap(b, d, hi);
      pA.u[0] = a; pA.u[1] = b; pA.u[2] = c; pA.u[3] = d;
    }
    {
      unsigned a = cvtpk(c0[8], c0[9]),  b = cvtpk(c0[10], c0[11]);
      unsigned c = cvtpk(c0[12], c0[13]), d = cvtpk(c0[14], c0[15]);
      plswap(a, c, hi); plswap(b, d, hi);
      pB.u[0] = a; pB.u[1] = b; pB.u[2] = c; pB.u[3] = d;
    }
    {
      unsigned a = cvtpk(c1[0], c1[1]), b = cvtpk(c1[2], c1[3]);
      unsigned c = cvtpk(c1[4], c1[5]), d = cvtpk(c1[6], c1[7]);
      plswap(a, c, hi); plswap(b, d, hi);
      pC.u[0] = a; pC.u[1] = b; pC.u[2] = c; pC.u[3] = d;
    }
    {
      unsigned a = cvtpk(c1[8], c1[9]),  b = cvtpk(c1[10], c1[11]);
      unsigned c = cvtpk(c1[12], c1[13]), d = cvtpk(c1[14], c1[15]);
      plswap(a, c, hi); plswap(b, d, hi);
      pD.u[0] = a; pD.u[1] = b; pD.u[2] = c; pD.u[3] = d;
    }

    __builtin_amdgcn_s_setprio(1);
    O = __builtin_amdgcn_mfma_f32_32x32x16_bf16(vf[0], pA.s, O, 0, 0, 0);
    O = __builtin_amdgcn_mfma_f32_32x32x16_bf16(vf[1], pB.s, O, 0, 0, 0);
    O = __builtin_amdgcn_mfma_f32_32x32x16_bf16(vf[2], pC.s, O, 0, 0, 0);
    O = __builtin_amdgcn_mfma_f32_32x32x16_bf16(vf[3], pD.s, O, 0, 0, 0);
    __builtin_amdgcn_s_setprio(0);

    kf[0] = kn[0]; kf[1] = kn[1]; kf[2] = kn[2]; kf[3] = kn[3];
    t = tn;
  }

  // ---- combine the 4 waves' partial (m, sum, O) ----
  #pragma unroll
  for (int i = 0; i < 16; ++i) {
    int d = (i & 3) + 8 * (i >> 2) + 4 * hi;
    Osh[w][d][qcol] = O[i];
  }
  if (hi == 0) { Msh[w][qcol] = m; Ssh[w][qcol] = sum; }
  __syncthreads();

  int tid = threadIdx.x;
  int q = tid & 31, dblk = tid >> 5;
  float m0 = Msh[0][q], m1 = Msh[1][q], m2 = Msh[2][q], m3 = Msh[3][q];
  float ms = fmaxf(fmaxf(m0, m1), fmaxf(m2, m3));
  float a0 = exp2f(m0 - ms), a1 = exp2f(m1 - ms);
  float a2 = exp2f(m2 - ms), a3 = exp2f(m3 - ms);
  float ss = a0 * Ssh[0][q] + a1 * Ssh[1][q] + a2 * Ssh[2][q] + a3 * Ssh[3][q];
  float inv = 1.0f / ss;
  #pragma unroll
  for (int r = 0; r < 4; ++r) {
    int d = dblk * 4 + r;
    float o = a0 * Osh[0][d][q] + a1 * Osh[1][d][q] +
              a2 * Osh[2][d][q] + a3 * Osh[3][d][q];
    out[((size_t)bh * HD + d) * LQ + q0b + q] = o * inv;
  }
}

extern "C" void kernel_launch(void* const* d_in, const int* in_sizes, int n_in,
                              void* d_out, int out_size, void* d_ws, size_t ws_size,
                              hipStream_t stream) {
  const float* query = (const float*)d_in[0];
  const float* key   = (const float*)d_in[1];
  const float* Wq    = (const float*)d_in[2];
  const float* bq    = (const float*)d_in[3];
  const float* Wk    = (const float*)d_in[4];
  const float* bk    = (const float*)d_in[5];
  const float* Wv    = (const float*)d_in[6];
  const float* bv    = (const float*)d_in[7];
  float* out = (float*)d_out;

  unsigned short* Wqb = (unsigned short*)d_ws;
  unsigned short* Wkb = Wqb + EMB * CIN;
  unsigned short* Wvb = Wkb + EMB * CIN;
  unsigned short* Xtq = Wvb + EMB * CIN;
  unsigned short* Xtk = Xtq + 2 * LQ * CIN;
  unsigned short* Qb  = Xtk + 2 * LQ * CIN;
  unsigned short* Kb  = Qb + 2 * NH * LQ * HD;
  unsigned short* Vt  = Kb + 2 * NH * LQ * HD;

  hipLaunchKernelGGL(k_prep, dim3(108, 2, 3), dim3(256), 0, stream,
                     query, key, Wq, Wk, Wv, Xtq, Xtk, Wqb, Wkb, Wvb);
  hipLaunchKernelGGL(k_proj, dim3(144, 2, 3), dim3(256), 0, stream,
                     Xtq, Xtk, Wqb, Wkb, Wvb, bq, bk, bv, Qb, Kb, Vt);
  hipLaunchKernelGGL(k_attn, dim3(1152), dim3(256), 0, stream,
                     Qb, Kb, Vt, out);
}